// Round 1
// baseline (59.412 us; speedup 1.0000x reference)
//
#include <hip/hip_runtime.h>

#define N_COMP 8192
#define N_PART 2048
#define THRESH 0.05f

__global__ __launch_bounds__(256) void pml_main(
    const float* __restrict__ completed,
    const float* __restrict__ partial,
    float* __restrict__ ws_sum,
    unsigned int* __restrict__ ws_cnt)
{
    const int batch = blockIdx.x >> 5;   // 32 blocks per batch
    const int chunk = blockIdx.x & 31;
    const int tid = threadIdx.x;

    __shared__ float4 sp[N_PART];        // 32 KB, padded float4 -> ds_read_b128 broadcast
    {
        const float* pb = partial + (size_t)batch * N_PART * 3;
        #pragma unroll
        for (int k = 0; k < N_PART / 256; ++k) {
            int j = k * 256 + tid;
            sp[j] = make_float4(pb[j * 3 + 0], pb[j * 3 + 1], pb[j * 3 + 2], 0.0f);
        }
    }
    __syncthreads();

    const int ci = (chunk << 8) + tid;   // completed index within batch
    const float* cb = completed + ((size_t)batch * N_COMP + ci) * 3;
    const float cx = cb[0], cy = cb[1], cz = cb[2];

    // 4 independent min chains: at 1 wave/SIMD a single serial v_min chain
    // (2048 deps x ~4 cyc) would dominate; 4 chains give the ILP.
    float m0 = 3.4028235e38f, m1 = m0, m2 = m0, m3 = m0;
    for (int j = 0; j < N_PART; j += 4) {
        float4 p0 = sp[j + 0];
        float4 p1 = sp[j + 1];
        float4 p2 = sp[j + 2];
        float4 p3 = sp[j + 3];
        float dx0 = cx - p0.x, dy0 = cy - p0.y, dz0 = cz - p0.z;
        float dx1 = cx - p1.x, dy1 = cy - p1.y, dz1 = cz - p1.z;
        float dx2 = cx - p2.x, dy2 = cy - p2.y, dz2 = cz - p2.z;
        float dx3 = cx - p3.x, dy3 = cy - p3.y, dz3 = cz - p3.z;
        float d0 = fmaf(dx0, dx0, fmaf(dy0, dy0, dz0 * dz0));
        float d1 = fmaf(dx1, dx1, fmaf(dy1, dy1, dz1 * dz1));
        float d2 = fmaf(dx2, dx2, fmaf(dy2, dy2, dz2 * dz2));
        float d3 = fmaf(dx3, dx3, fmaf(dy3, dy3, dz3 * dz3));
        m0 = fminf(m0, d0);
        m1 = fminf(m1, d1);
        m2 = fminf(m2, d2);
        m3 = fminf(m3, d3);
    }
    float m = fminf(fminf(m0, m1), fminf(m2, m3));

    float        v = (m < THRESH) ? m : 0.0f;
    unsigned int c = (m < THRESH) ? 1u : 0u;

    // wave64 butterfly-style down-reduce
    #pragma unroll
    for (int off = 32; off >= 1; off >>= 1) {
        v += __shfl_down(v, off, 64);
        c += __shfl_down(c, off, 64);
    }

    __shared__ float        lsum[4];
    __shared__ unsigned int lcnt[4];
    const int wave = tid >> 6;
    const int lane = tid & 63;
    if (lane == 0) { lsum[wave] = v; lcnt[wave] = c; }
    __syncthreads();
    if (tid == 0) {
        float        bs = lsum[0] + lsum[1] + lsum[2] + lsum[3];
        unsigned int bc = lcnt[0] + lcnt[1] + lcnt[2] + lcnt[3];
        atomicAdd(ws_sum, bs);
        atomicAdd(ws_cnt, bc);
    }
}

__global__ void pml_fin(const float* __restrict__ ws_sum,
                        const unsigned int* __restrict__ ws_cnt,
                        float* __restrict__ out)
{
    float s = *ws_sum;
    unsigned int c = *ws_cnt;
    float loss = (c > 0u) ? (s / ((float)c + 1e-6f)) : 0.0f;
    *out = loss;   // WEIGHT = 1.0
}

extern "C" void kernel_launch(void* const* d_in, const int* in_sizes, int n_in,
                              void* d_out, int out_size, void* d_ws, size_t ws_size,
                              hipStream_t stream) {
    const float* completed = (const float*)d_in[0];  // (8, 8192, 3) f32
    const float* partial   = (const float*)d_in[1];  // (8, 2048, 3) f32
    float*        out    = (float*)d_out;            // scalar f32
    float*        ws_sum = (float*)d_ws;
    unsigned int* ws_cnt = (unsigned int*)d_ws + 1;

    // ws is poisoned 0xAA and never re-poisoned between replays: zero it
    // ourselves every call (memset node is graph-capture safe).
    hipMemsetAsync(d_ws, 0, 2 * sizeof(float), stream);

    pml_main<<<dim3(256), dim3(256), 0, stream>>>(completed, partial, ws_sum, ws_cnt);
    pml_fin<<<1, 1, 0, stream>>>(ws_sum, ws_cnt, out);
}

// Round 3
// 32.556 us; speedup vs baseline: 1.8249x; 1.8249x over previous
//
#include <hip/hip_runtime.h>

#define NPART   2048
#define NCOMP   8192
#define SLOTS   64                       // point-slots per block
#define SEGS    16                       // partial segments (one per wave-group)
#define SEGLEN  (NPART / SEGS)           // 128 partials per segment
#define PPT     4                        // completed points per thread
#define PTSBLK  (SLOTS * PPT)            // 256 completed points per block
#define THRESH  0.05f
#define FLTMAX  3.4028235e38f

__global__ __launch_bounds__(1024, 4) void pml_main(
    const float* __restrict__ completed,
    const float* __restrict__ partial,
    float* __restrict__ ws_sum,
    unsigned int* __restrict__ ws_cnt)
{
    const int tid   = threadIdx.x;
    const int slot  = tid & (SLOTS - 1);
    const int seg   = tid >> 6;              // 0..15, uniform within each wave64
    const int batch = blockIdx.x >> 5;       // 32 blocks per batch
    const int blkb  = blockIdx.x & 31;       // block within batch

    __shared__ float4 sp[NPART];             // 32 KB: (x,y,z,|p|^2)
    __shared__ float  smin[PTSBLK][SEGS + 1];// 17 KB, pad 17 -> 2-way banks (free)
    __shared__ float  sc2[PTSBLK];           // 1 KB
    __shared__ float        rs[4];
    __shared__ unsigned int rc[4];

    // ---- stage partials: 1024 threads x 2 points, precompute |p|^2 ----
    {
        const float* pb = partial + (size_t)batch * NPART * 3;
        #pragma unroll
        for (int k = 0; k < 2; ++k) {
            int j = k * 1024 + tid;
            float x = pb[3 * j + 0];
            float y = pb[3 * j + 1];
            float z = pb[3 * j + 2];
            sp[j] = make_float4(x, y, z, fmaf(x, x, fmaf(y, y, z * z)));
        }
    }

    // ---- this thread's 4 completed points (stride-64 -> coalesced loads) ----
    const float* cb = completed + ((size_t)batch * NCOMP + (size_t)blkb * PTSBLK) * 3;
    float nx[PPT], ny[PPT], nz[PPT], c2[PPT];
    #pragma unroll
    for (int k = 0; k < PPT; ++k) {
        int p = slot + k * SLOTS;
        float x = cb[3 * p + 0];
        float y = cb[3 * p + 1];
        float z = cb[3 * p + 2];
        nx[k] = -2.0f * x;
        ny[k] = -2.0f * y;
        nz[k] = -2.0f * z;
        c2[k] = fmaf(x, x, fmaf(y, y, z * z));
    }

    __syncthreads();

    // ---- scan this wave's 128-partial segment for 4 points ----
    // t = |p|^2 - 2 c.p ; min-reduce. 16 independent chains (4 pts x 4 unroll).
    const float4* s = sp + seg * SEGLEN;
    float acc[PPT][4];
    #pragma unroll
    for (int k = 0; k < PPT; ++k)
        #pragma unroll
        for (int u = 0; u < 4; ++u) acc[k][u] = FLTMAX;

    for (int j = 0; j < SEGLEN; j += 4) {
        float4 p0 = s[j + 0];
        float4 p1 = s[j + 1];
        float4 p2 = s[j + 2];
        float4 p3 = s[j + 3];
        #pragma unroll
        for (int k = 0; k < PPT; ++k) {
            acc[k][0] = fminf(acc[k][0], fmaf(p0.x, nx[k], fmaf(p0.y, ny[k], fmaf(p0.z, nz[k], p0.w))));
            acc[k][1] = fminf(acc[k][1], fmaf(p1.x, nx[k], fmaf(p1.y, ny[k], fmaf(p1.z, nz[k], p1.w))));
            acc[k][2] = fminf(acc[k][2], fmaf(p2.x, nx[k], fmaf(p2.y, ny[k], fmaf(p2.z, nz[k], p2.w))));
            acc[k][3] = fminf(acc[k][3], fmaf(p3.x, nx[k], fmaf(p3.y, ny[k], fmaf(p3.z, nz[k], p3.w))));
        }
    }

    #pragma unroll
    for (int k = 0; k < PPT; ++k) {
        float t = fminf(fminf(acc[k][0], acc[k][1]), fminf(acc[k][2], acc[k][3]));
        smin[slot + k * SLOTS][seg] = t;
        if (seg == 0) sc2[slot + k * SLOTS] = c2[k];
    }
    __syncthreads();

    // ---- combine 16 segments per point, mask, block-reduce ----
    float        v = 0.0f;
    unsigned int c = 0u;
    if (tid < PTSBLK) {
        float t = smin[tid][0];
        #pragma unroll
        for (int g = 1; g < SEGS; ++g) t = fminf(t, smin[tid][g]);
        float m = fmaxf(sc2[tid] + t, 0.0f);
        if (m < THRESH) { v = m; c = 1u; }
        #pragma unroll
        for (int off = 32; off >= 1; off >>= 1) {
            v += __shfl_down(v, off, 64);
            c += __shfl_down(c, off, 64);
        }
        if ((tid & 63) == 0) { rs[tid >> 6] = v; rc[tid >> 6] = c; }
    }
    __syncthreads();
    if (tid == 0) {
        atomicAdd(ws_sum, rs[0] + rs[1] + rs[2] + rs[3]);
        atomicAdd(ws_cnt, rc[0] + rc[1] + rc[2] + rc[3]);
    }
}

__global__ void pml_fin(const float* __restrict__ ws_sum,
                        const unsigned int* __restrict__ ws_cnt,
                        float* __restrict__ out)
{
    float s = *ws_sum;
    unsigned int c = *ws_cnt;
    float loss = (c > 0u) ? (s / ((float)c + 1e-6f)) : 0.0f;
    *out = loss;   // WEIGHT = 1.0
}

extern "C" void kernel_launch(void* const* d_in, const int* in_sizes, int n_in,
                              void* d_out, int out_size, void* d_ws, size_t ws_size,
                              hipStream_t stream) {
    const float* completed = (const float*)d_in[0];  // (8, 8192, 3) f32
    const float* partial   = (const float*)d_in[1];  // (8, 2048, 3) f32
    float*        out    = (float*)d_out;            // scalar f32
    float*        ws_sum = (float*)d_ws;
    unsigned int* ws_cnt = (unsigned int*)d_ws + 1;

    // ws is poisoned 0xAA and never re-poisoned between replays: zero the
    // accumulators every call (memset node is graph-capture safe).
    hipMemsetAsync(d_ws, 0, 2 * sizeof(float), stream);

    // 8 batches x 32 blocks, 256 points per block, 1024 threads (16 waves).
    pml_main<<<dim3(256), dim3(1024), 0, stream>>>(completed, partial, ws_sum, ws_cnt);
    pml_fin<<<1, 1, 0, stream>>>(ws_sum, ws_cnt, out);
}